// Round 3
// baseline (13692.032 us; speedup 1.0000x reference)
//
#include <hip/hip_runtime.h>
#include <cmath>

#define B 128
#define T 128
#define H 512
#define TGT 32

// ---------------------------------------------------------------------------
// init: zero parity-0 state (all 4 layers) of the unified state buffer.
// state layout: [parity][4][B][H] fp32. enc0 uses layers {0,1} (dirs),
// enc1 layers {2,3} — encoder finals land exactly where the decoder expects
// hn = [hf0, hb0, hf1, hb1].
// ---------------------------------------------------------------------------
__global__ void kinit(float* __restrict__ st) {
    int idx = blockIdx.x * 256 + threadIdx.x;          // 32768 threads
    for (int i = idx; i < 4 * B * H; i += 32768) st[i] = 0.0f;
}

// ---------------------------------------------------------------------------
// Encoder layer 0, one time step (both directions), fp32.
// grid: 256 = dir(2) x btile(8,Mb=16) x ntile(16,Ns=32); 256 thr, 2 out/thr
// ---------------------------------------------------------------------------
__global__ __launch_bounds__(256) void enc0_step(
    const float* __restrict__ x, const float* __restrict__ Wih,
    const float* __restrict__ Whh, const float* __restrict__ bih,
    const float* __restrict__ bhh, float* __restrict__ st,
    float* __restrict__ l0, int s)
{
    __shared__ float hs[16 * H];
    int bx = blockIdx.x;
    int dir = bx >> 7, rem = bx & 127;
    int b0 = (rem >> 4) * 16, n0 = (rem & 15) * 32;
    int tid = threadIdx.x;
    int p = s & 1;

    const float4* src = (const float4*)(st + ((size_t)(p * 4 + dir) * B + b0) * H);
    float4* dst = (float4*)hs;
#pragma unroll
    for (int i = 0; i < 8; i++) dst[tid + 256 * i] = src[tid + 256 * i];
    __syncthreads();

    int bl = tid >> 5, nl = tid & 31;
    int n = n0 + nl, b1 = b0 + bl, b2 = b1 + 8;
    int t = dir ? (T - 1 - s) : s;

    float bias = bih[dir * H + n] + bhh[dir * H + n];
    const float* wih = Wih + (size_t)(dir * H + n) * 3;
    float w0 = wih[0], w1 = wih[1], w2 = wih[2];
    const float* xr1 = x + ((size_t)b1 * T + t) * 3;
    const float* xr2 = x + ((size_t)b2 * T + t) * 3;
    float a1 = bias + xr1[0] * w0 + xr1[1] * w1 + xr1[2] * w2;
    float a2 = bias + xr2[0] * w0 + xr2[1] * w1 + xr2[2] * w2;

    // 4 partial accumulators per output to reduce summation-order noise
    float p1x = 0, p1y = 0, p1z = 0, p1w = 0;
    float p2x = 0, p2y = 0, p2z = 0, p2w = 0;
    const float* wr = Whh + (size_t)(dir * H + n) * H;
    const float* h1 = hs + bl * H;
    const float* h2 = hs + (bl + 8) * H;
#pragma unroll 4
    for (int k = 0; k < H; k += 4) {
        float4 w4 = *(const float4*)(wr + k);
        float4 f1 = *(const float4*)(h1 + k);
        float4 f2 = *(const float4*)(h2 + k);
        p1x += w4.x * f1.x; p1y += w4.y * f1.y; p1z += w4.z * f1.z; p1w += w4.w * f1.w;
        p2x += w4.x * f2.x; p2y += w4.y * f2.y; p2z += w4.z * f2.z; p2w += w4.w * f2.w;
    }
    a1 += (p1x + p1y) + (p1z + p1w);
    a2 += (p2x + p2y) + (p2z + p2w);
    float o1 = tanhf(a1), o2 = tanhf(a2);
    float* hw = st + (size_t)((1 - p) * 4 + dir) * B * H;
    hw[(size_t)b1 * H + n] = o1;
    hw[(size_t)b2 * H + n] = o2;
    l0[((size_t)t * B + b1) * 1024 + dir * H + n] = o1;
    l0[((size_t)t * B + b2) * 1024 + dir * H + n] = o2;
}

// ---------------------------------------------------------------------------
// Encoder layer 1, one time step (both directions). State layers {2,3}.
// Input projection over l0[t] (K=1024) folded in.
// ---------------------------------------------------------------------------
__global__ __launch_bounds__(256) void enc1_step(
    const float* __restrict__ Wih, const float* __restrict__ Whh,
    const float* __restrict__ bih, const float* __restrict__ bhh,
    float* __restrict__ st, const float* __restrict__ l0, int s)
{
    __shared__ float hs[16 * H];
    int bx = blockIdx.x;
    int dir = bx >> 7, rem = bx & 127;
    int b0 = (rem >> 4) * 16, n0 = (rem & 15) * 32;
    int tid = threadIdx.x;
    int p = s & 1;

    const float4* src = (const float4*)(st + ((size_t)(p * 4 + 2 + dir) * B + b0) * H);
    float4* dst = (float4*)hs;
#pragma unroll
    for (int i = 0; i < 8; i++) dst[tid + 256 * i] = src[tid + 256 * i];
    __syncthreads();

    int bl = tid >> 5, nl = tid & 31;
    int n = n0 + nl, b1 = b0 + bl, b2 = b1 + 8;
    int t = dir ? (T - 1 - s) : s;

    float p1x = 0, p1y = 0, p1z = 0, p1w = 0;
    float p2x = 0, p2y = 0, p2z = 0, p2w = 0;

    const float* wi = Wih + (size_t)(dir * H + n) * 1024;
    const float* x1 = l0 + ((size_t)t * B + b1) * 1024;
    const float* x2 = l0 + ((size_t)t * B + b2) * 1024;
#pragma unroll 4
    for (int k = 0; k < 1024; k += 4) {
        float4 w4 = *(const float4*)(wi + k);
        float4 q1 = *(const float4*)(x1 + k);
        float4 q2 = *(const float4*)(x2 + k);
        p1x += w4.x * q1.x; p1y += w4.y * q1.y; p1z += w4.z * q1.z; p1w += w4.w * q1.w;
        p2x += w4.x * q2.x; p2y += w4.y * q2.y; p2z += w4.z * q2.z; p2w += w4.w * q2.w;
    }
    const float* wr = Whh + (size_t)(dir * H + n) * H;
    const float* h1 = hs + bl * H;
    const float* h2 = hs + (bl + 8) * H;
#pragma unroll 4
    for (int k = 0; k < H; k += 4) {
        float4 w4 = *(const float4*)(wr + k);
        float4 f1 = *(const float4*)(h1 + k);
        float4 f2 = *(const float4*)(h2 + k);
        p1x += w4.x * f1.x; p1y += w4.y * f1.y; p1z += w4.z * f1.z; p1w += w4.w * f1.w;
        p2x += w4.x * f2.x; p2y += w4.y * f2.y; p2z += w4.z * f2.z; p2w += w4.w * f2.w;
    }
    float bias = bih[dir * H + n] + bhh[dir * H + n];
    float a1 = bias + (p1x + p1y) + (p1z + p1w);
    float a2 = bias + (p2x + p2y) + (p2z + p2w);
    float* hw = st + (size_t)((1 - p) * 4 + 2 + dir) * B * H;
    hw[(size_t)b1 * H + n] = tanhf(a1);
    hw[(size_t)b2 * H + n] = tanhf(a2);
}

// ---------------------------------------------------------------------------
// Decoder step, layer 0 + previous step's head (o0/xin recurrence, dout).
// grid 256 = btile(8,Mb=16) x ntile(32,Ns=16). xing: [2][B][4] fp32 ping-pong.
// ---------------------------------------------------------------------------
__global__ __launch_bounds__(256) void dec_step0(
    const float* __restrict__ x, const float* __restrict__ Wih0,
    const float* __restrict__ Whh, const float* __restrict__ bih,
    const float* __restrict__ bhh, const float* __restrict__ linW,
    const float* __restrict__ linb, float* __restrict__ dech,
    float* __restrict__ xing, float* __restrict__ dout, int s)
{
    __shared__ float hs[16 * H];
    __shared__ float xinL[16][3];
    int bx = blockIdx.x;
    int bt = bx >> 5, nt = bx & 31;
    int b0 = bt * 16, n0 = nt * 16;
    int tid = threadIdx.x;
    int p = s & 1, q = 1 - p;
    int r = tid >> 4, l16 = tid & 15;
    int b = b0 + r, n = n0 + l16;

    if (s == 0) {
        if (tid < 48) {
            int rr = tid / 3, j = tid - rr * 3;
            float v = x[((size_t)(b0 + rr) * T + (T - 1)) * 3 + j];
            xinL[rr][j] = v;
            if (nt == 0) xing[(size_t)(b0 + rr) * 4 + j] = v;  // parity 0
        }
    } else {
        const float* h3r = dech + ((size_t)(p * 4 + 3) * B + b) * H;
        float ss = 0.0f;
        for (int j = l16; j < H; j += 16) ss += h3r[j] * linW[j];
#pragma unroll
        for (int o = 8; o >= 1; o >>= 1) ss += __shfl_xor(ss, o, 16);
        if (l16 == 0) {
            float o0 = ss + linb[0];
            const float* xp = xing + (size_t)((s - 1) & 1) * B * 4 + (size_t)b * 4;
            float s1 = xp[0] - o0;
            float s2 = xp[1] - s1;
            xinL[r][0] = o0; xinL[r][1] = s1; xinL[r][2] = s2;
            if (nt == 0) {
                float* xw = xing + (size_t)(s & 1) * B * 4 + (size_t)b * 4;
                xw[0] = o0; xw[1] = s1; xw[2] = s2;
                dout[(size_t)b * TGT + (s - 1)] = o0;
            }
        }
    }
    __syncthreads();

    const float4* src = (const float4*)(dech + ((size_t)(p * 4 + 0) * B + b0) * H);
    float4* dst = (float4*)hs;
#pragma unroll
    for (int i = 0; i < 8; i++) dst[tid + 256 * i] = src[tid + 256 * i];
    __syncthreads();

    float acc = bih[0 * H + n] + bhh[0 * H + n];
    const float* wi = Wih0 + (size_t)n * 3;
    acc += xinL[r][0] * wi[0] + xinL[r][1] * wi[1] + xinL[r][2] * wi[2];

    float px = 0, py = 0, pz = 0, pw = 0;
    const float* wh = Whh + (size_t)(0 * H + n) * H;
    const float* hr = hs + r * H;
#pragma unroll 4
    for (int k = 0; k < H; k += 4) {
        float4 w4 = *(const float4*)(wh + k);
        float4 f = *(const float4*)(hr + k);
        px += w4.x * f.x; py += w4.y * f.y; pz += w4.z * f.z; pw += w4.w * f.w;
    }
    acc += (px + py) + (pz + pw);
    dech[((size_t)(q * 4 + 0) * B + b) * H + n] = tanhf(acc);
}

// ---------------------------------------------------------------------------
// Decoder step, layers 1..3
// ---------------------------------------------------------------------------
__global__ __launch_bounds__(256) void dec_stepL(
    const float* __restrict__ Wihr, const float* __restrict__ Whh,
    const float* __restrict__ bih, const float* __restrict__ bhh,
    float* __restrict__ dech, int s, int l)
{
    __shared__ float hs[16 * H];
    int bx = blockIdx.x;
    int bt = bx >> 5, nt = bx & 31;
    int b0 = bt * 16, n0 = nt * 16;
    int tid = threadIdx.x;
    int p = s & 1, q = 1 - p;
    int r = tid >> 4, l16 = tid & 15;
    int b = b0 + r, n = n0 + l16;

    const float4* src = (const float4*)(dech + ((size_t)(p * 4 + l) * B + b0) * H);
    float4* dst = (float4*)hs;
#pragma unroll
    for (int i = 0; i < 8; i++) dst[tid + 256 * i] = src[tid + 256 * i];
    __syncthreads();

    const float* hin = dech + ((size_t)(q * 4 + (l - 1)) * B + b) * H;
    const float* wi = Wihr + (size_t)((l - 1) * H + n) * H;
    const float* wh = Whh + (size_t)(l * H + n) * H;
    const float* hr = hs + r * H;
    float px = 0, py = 0, pz = 0, pw = 0;
#pragma unroll 4
    for (int k = 0; k < H; k += 4) {
        float4 wi4 = *(const float4*)(wi + k);
        float4 wh4 = *(const float4*)(wh + k);
        float4 xi = *(const float4*)(hin + k);
        float4 hh = *(const float4*)(hr + k);
        px += wi4.x * xi.x + wh4.x * hh.x;
        py += wi4.y * xi.y + wh4.y * hh.y;
        pz += wi4.z * xi.z + wh4.z * hh.z;
        pw += wi4.w * xi.w + wh4.w * hh.w;
    }
    float acc = bih[l * H + n] + bhh[l * H + n] + (px + py) + (pz + pw);
    dech[((size_t)(q * 4 + l) * B + b) * H + n] = tanhf(acc);
}

// ---------------------------------------------------------------------------
// Final head: out[b][31] from dech parity0 layer3
// ---------------------------------------------------------------------------
__global__ void dec_fin(const float* __restrict__ dech, const float* __restrict__ linW,
                        const float* __restrict__ linb, float* __restrict__ dout)
{
    int b = blockIdx.x;
    int tid = threadIdx.x;
    const float* h3r = dech + ((size_t)(0 * 4 + 3) * B + b) * H;
    float ss = 0.0f;
    for (int j = tid; j < H; j += 64) ss += h3r[j] * linW[j];
#pragma unroll
    for (int o = 32; o >= 1; o >>= 1) ss += __shfl_xor(ss, o, 64);
    if (tid == 0) dout[(size_t)b * TGT + 31] = ss + linb[0];
}

// ---------------------------------------------------------------------------
extern "C" void kernel_launch(void* const* d_in, const int* in_sizes, int n_in,
                              void* d_out, int out_size, void* d_ws, size_t ws_size,
                              hipStream_t stream)
{
    const float* x     = (const float*)d_in[0];
    // d_in[1] = y (unused: teacher_forcing_ratio == 0)
    const float* eWih0 = (const float*)d_in[2];
    const float* eWhh0 = (const float*)d_in[3];
    const float* eWih1 = (const float*)d_in[4];
    const float* eWhh1 = (const float*)d_in[5];
    const float* ebih  = (const float*)d_in[6];
    const float* ebhh  = (const float*)d_in[7];
    const float* dWih0 = (const float*)d_in[8];
    const float* dWihr = (const float*)d_in[9];
    const float* dWhh  = (const float*)d_in[10];
    const float* dbih  = (const float*)d_in[11];
    const float* dbhh  = (const float*)d_in[12];
    const float* linW  = (const float*)d_in[13];
    const float* linb  = (const float*)d_in[14];
    float* dout = (float*)d_out;

    // ws layout (~66.1 MB): dech[2][4][B][H] f32 | xing[2][B][4] f32 |
    //                       l0[T][B][1024] f32
    float* dech = (float*)d_ws;
    float* xing = dech + 2 * 4 * B * H;
    float* l0   = xing + 2 * B * 4;

    kinit<<<128, 256, 0, stream>>>(dech);

    for (int s = 0; s < T; s++)
        enc0_step<<<256, 256, 0, stream>>>(x, eWih0, eWhh0, ebih, ebhh, dech, l0, s);
    for (int s = 0; s < T; s++)
        enc1_step<<<256, 256, 0, stream>>>(eWih1, eWhh1, ebih + 2 * H, ebhh + 2 * H,
                                           dech, l0, s);

    for (int s = 0; s < TGT; s++) {
        dec_step0<<<256, 256, 0, stream>>>(x, dWih0, dWhh, dbih, dbhh, linW, linb,
                                           dech, xing, dout, s);
        for (int l = 1; l < 4; l++)
            dec_stepL<<<256, 256, 0, stream>>>(dWihr, dWhh, dbih, dbhh, dech, s, l);
    }
    dec_fin<<<128, 64, 0, stream>>>(dech, linW, linb, dout);
}

// Round 4
// 10933.679 us; speedup vs baseline: 1.2523x; 1.2523x over previous
//
#include <hip/hip_runtime.h>
#include <cmath>

#define B 128
#define T 128
#define H 512
#define TGT 32

#define SCOPE_AGENT __HIP_MEMORY_SCOPE_AGENT

struct Args {
  const float *x, *eWih0, *eWhh0, *eWih1, *eWhh1, *ebih, *ebhh;
  const float *dWih0, *dWihr, *dWhh, *dbih, *dbhh, *linW, *linb;
  float *dst;    // dstate [2 parity][4 layer][B][H]
  float *xing;   // [2][B][4]
  float *l0;     // [T][B][1024]  (overwritten in place by G1 = proj + biases)
  unsigned *ctr; // [64]: 0..15 E0 groups, 16..31 E1 groups, 32..39 DEC groups, 40 grid
  float *out;    // [B][TGT]
};

// ---------------------------------------------------------------------------
__global__ void kinit(float* __restrict__ st, unsigned* __restrict__ ctr) {
  int idx = blockIdx.x * 256 + threadIdx.x;
  for (int i = idx; i < 4 * B * H; i += 256 * 256) st[i] = 0.f;  // parity-0 state
  if (idx < 64) ctr[idx] = 0u;
}

// ---------------------------------------------------------------------------
__device__ __forceinline__ void bump(unsigned* c) {
  __syncthreads();  // all block stores drained (vmcnt0 at barrier) before release
  if (threadIdx.x == 0)
    __hip_atomic_fetch_add(c, 1u, __ATOMIC_RELEASE, SCOPE_AGENT);
}
__device__ __forceinline__ void waitc(unsigned* c, unsigned tgt) {
  if (threadIdx.x == 0)
    while (__hip_atomic_load(c, __ATOMIC_ACQUIRE, SCOPE_AGENT) < tgt)
      __builtin_amdgcn_s_sleep(2);
  __syncthreads();
}

// stage rows (ROWLEN floats each, global row stride GSTRIDE) into LDS w/ lstride
template <int ROWLEN, int GSTRIDE>
__device__ __forceinline__ void stage(const float* __restrict__ g,
                                      float* __restrict__ l, int rows, int lstride) {
  int total = rows * ROWLEN;
  for (int idx = (int)threadIdx.x * 4; idx < total; idx += 1024) {
    int r = idx / ROWLEN, k = idx - r * ROWLEN;
    float4 v = *(const float4*)(g + (size_t)r * GSTRIDE + k);
    *(float4*)(l + r * lstride + k) = v;
  }
}

// ---------------------------------------------------------------------------
__global__ __launch_bounds__(256, 1) void birnn_all(Args a) {
  __shared__ __align__(16) float sm[33088];   // 132352 B, unioned per phase
  const int tid = threadIdx.x;
  const int bx = blockIdx.x;

  //========================= ENCODER LAYER 0 ================================
  {
    const int dir = bx >> 7, btile = (bx >> 4) & 7, ntile = bx & 15;
    const int b0 = btile * 16, n0 = ntile * 32;
    const int j = tid & 15, bl = tid >> 4;
    const int n1 = n0 + j, n2 = n0 + j + 16;   // strided n-pair: 2-way banks = free
    float* wl = sm;          // [32][516]
    float* hl = sm + 16512;  // [16][516]
    unsigned* c = a.ctr + dir * 8 + btile;

    stage<512, 512>(a.eWhh0 + (size_t)(dir * H + n0) * H, wl, 32, 516);
    float wx0[3], wx1[3];
#pragma unroll
    for (int i = 0; i < 3; i++) {
      wx0[i] = a.eWih0[(dir * H + n1) * 3 + i];
      wx1[i] = a.eWih0[(dir * H + n2) * 3 + i];
    }
    float bias0 = a.ebih[dir * H + n1] + a.ebhh[dir * H + n1];
    float bias1 = a.ebih[dir * H + n2] + a.ebhh[dir * H + n2];

    for (int s = 0; s < T; s++) {
      if (s) waitc(c, 16u * s); else __syncthreads();
      stage<512, 512>(a.dst + ((size_t)((s & 1) * 4 + dir) * B + b0) * H, hl, 16, 516);
      __syncthreads();
      int t = dir ? (T - 1 - s) : s;
      const float* xr = a.x + ((size_t)(b0 + bl) * T + t) * 3;
      float x0 = xr[0], x1 = xr[1], x2 = xr[2];
      float a1 = bias0 + x0 * wx0[0] + x1 * wx0[1] + x2 * wx0[2];
      float a2 = bias1 + x0 * wx1[0] + x1 * wx1[1] + x2 * wx1[2];
      const float* hr = hl + bl * 516;
      const float* w1r = wl + j * 516;
      const float* w2r = wl + (j + 16) * 516;
      float s1x = 0, s1y = 0, s1z = 0, s1w = 0, s2x = 0, s2y = 0, s2z = 0, s2w = 0;
#pragma unroll 4
      for (int k = 0; k < H; k += 4) {
        float4 hv = *(const float4*)(hr + k);
        float4 wa = *(const float4*)(w1r + k);
        float4 wb = *(const float4*)(w2r + k);
        s1x += wa.x * hv.x; s1y += wa.y * hv.y; s1z += wa.z * hv.z; s1w += wa.w * hv.w;
        s2x += wb.x * hv.x; s2y += wb.y * hv.y; s2z += wb.z * hv.z; s2w += wb.w * hv.w;
      }
      float o1 = tanhf(a1 + (s1x + s1y) + (s1z + s1w));
      float o2 = tanhf(a2 + (s2x + s2y) + (s2z + s2w));
      float* hw = a.dst + ((size_t)(((s + 1) & 1) * 4 + dir) * B + (b0 + bl)) * H;
      hw[n1] = o1; hw[n2] = o2;
      float* lr = a.l0 + ((size_t)t * B + (b0 + bl)) * 1024 + dir * H;
      lr[n1] = o1; lr[n2] = o2;
      bump(c);
    }
  }
  { unsigned* g = a.ctr + 40; bump(g); waitc(g, 256u); }  // grid barrier 1

  //===================== ENC1 INPUT PROJECTION (in-place G1) ================
  {
    float* xl = sm;          // [16][1028]  full-K row slab
    float* wl = sm + 16448;  // [64][260]
    const int rl = tid >> 4, ng = tid & 15;
    for (int rt = 0; rt < 4; rt++) {
      int row0 = (bx * 4 + rt) * 16;
      __syncthreads();
      stage<1024, 1024>(a.l0 + (size_t)row0 * 1024, xl, 16, 1028);
      __syncthreads();
      for (int nc = 0; nc < 16; nc++) {
        float acc0, acc1, acc2, acc3;
        {
          int nb = nc * 64 + ng;
          int nA = nb, nB = nb + 16, nC = nb + 32, nD = nb + 48;
          acc0 = a.ebih[(2 + (nA >> 9)) * H + (nA & 511)] + a.ebhh[(2 + (nA >> 9)) * H + (nA & 511)];
          acc1 = a.ebih[(2 + (nB >> 9)) * H + (nB & 511)] + a.ebhh[(2 + (nB >> 9)) * H + (nB & 511)];
          acc2 = a.ebih[(2 + (nC >> 9)) * H + (nC & 511)] + a.ebhh[(2 + (nC >> 9)) * H + (nC & 511)];
          acc3 = a.ebih[(2 + (nD >> 9)) * H + (nD & 511)] + a.ebhh[(2 + (nD >> 9)) * H + (nD & 511)];
        }
        for (int kp = 0; kp < 4; kp++) {
          __syncthreads();
          stage<256, 1024>(a.eWih1 + (size_t)(nc * 64) * 1024 + kp * 256, wl, 64, 260);
          __syncthreads();
          const float* xrow = xl + rl * 1028 + kp * 256;
          const float* w0 = wl + ng * 260;
#pragma unroll 4
          for (int k = 0; k < 256; k += 4) {
            float4 xv = *(const float4*)(xrow + k);
            float4 wa = *(const float4*)(w0 + k);
            float4 wb = *(const float4*)(w0 + 16 * 260 + k);
            float4 wc = *(const float4*)(w0 + 32 * 260 + k);
            float4 wd = *(const float4*)(w0 + 48 * 260 + k);
            acc0 += wa.x * xv.x + wa.y * xv.y + wa.z * xv.z + wa.w * xv.w;
            acc1 += wb.x * xv.x + wb.y * xv.y + wb.z * xv.z + wb.w * xv.w;
            acc2 += wc.x * xv.x + wc.y * xv.y + wc.z * xv.z + wc.w * xv.w;
            acc3 += wd.x * xv.x + wd.y * xv.y + wd.z * xv.z + wd.w * xv.w;
          }
        }
        float* gr = a.l0 + (size_t)(row0 + rl) * 1024 + nc * 64;
        gr[ng] = acc0; gr[ng + 16] = acc1; gr[ng + 32] = acc2; gr[ng + 48] = acc3;
      }
    }
  }
  { unsigned* g = a.ctr + 40; bump(g); waitc(g, 512u); }  // grid barrier 2

  //========================= ENCODER LAYER 1 ================================
  {
    const int dir = bx >> 7, btile = (bx >> 4) & 7, ntile = bx & 15;
    const int b0 = btile * 16, n0 = ntile * 32;
    const int j = tid & 15, bl = tid >> 4;
    const int n1 = n0 + j, n2 = n0 + j + 16;
    float* wl = sm;
    float* hl = sm + 16512;
    unsigned* c = a.ctr + 16 + dir * 8 + btile;

    stage<512, 512>(a.eWhh1 + (size_t)(dir * H + n0) * H, wl, 32, 516);

    for (int s = 0; s < T; s++) {
      if (s) waitc(c, 16u * s); else __syncthreads();
      stage<512, 512>(a.dst + ((size_t)((s & 1) * 4 + 2 + dir) * B + b0) * H, hl, 16, 516);
      __syncthreads();
      int t = dir ? (T - 1 - s) : s;
      const float* g1 = a.l0 + ((size_t)t * B + (b0 + bl)) * 1024 + dir * H;
      float a1 = g1[n1];   // G1 already includes bih+bhh
      float a2 = g1[n2];
      const float* hr = hl + bl * 516;
      const float* w1r = wl + j * 516;
      const float* w2r = wl + (j + 16) * 516;
      float s1x = 0, s1y = 0, s1z = 0, s1w = 0, s2x = 0, s2y = 0, s2z = 0, s2w = 0;
#pragma unroll 4
      for (int k = 0; k < H; k += 4) {
        float4 hv = *(const float4*)(hr + k);
        float4 wa = *(const float4*)(w1r + k);
        float4 wb = *(const float4*)(w2r + k);
        s1x += wa.x * hv.x; s1y += wa.y * hv.y; s1z += wa.z * hv.z; s1w += wa.w * hv.w;
        s2x += wb.x * hv.x; s2y += wb.y * hv.y; s2z += wb.z * hv.z; s2w += wb.w * hv.w;
      }
      float o1 = tanhf(a1 + (s1x + s1y) + (s1z + s1w));
      float o2 = tanhf(a2 + (s2x + s2y) + (s2z + s2w));
      float* hw = a.dst + ((size_t)(((s + 1) & 1) * 4 + 2 + dir) * B + (b0 + bl)) * H;
      hw[n1] = o1; hw[n2] = o2;
      bump(c);
    }
  }
  { unsigned* g = a.ctr + 40; bump(g); waitc(g, 768u); }  // grid barrier 3

  //============================== DECODER ===================================
  {
    const int btile = bx >> 5, ntile = bx & 31;
    const int b0 = btile * 16, n0 = ntile * 16;
    const int j = tid & 15, bl = tid >> 4;
    const int n = n0 + j;
    float* whh  = sm;           // [16][516]
    float* wir  = sm + 8256;    // [16][516]
    float* hlc  = sm + 16512;   // [16][516] old state of current layer
    float* hin  = sm + 24768;   // [16][516] prev-layer new state (or h3 at l==0)
    float* xinL = sm + 33024;   // [16][4]
    unsigned* c = a.ctr + 32 + btile;

    float w00 = a.dWih0[n * 3 + 0], w01 = a.dWih0[n * 3 + 1], w02 = a.dWih0[n * 3 + 2];
    float bias[4];
#pragma unroll
    for (int l = 0; l < 4; l++) bias[l] = a.dbih[l * H + n] + a.dbhh[l * H + n];

    for (int m = 0; m < 128; m++) {
      int s = m >> 2, l = m & 3;
      int p = s & 1, q = 1 - p;
      if (m) waitc(c, 32u * m); else __syncthreads();

      stage<512, 512>(a.dWhh + (size_t)(l * H + n0) * H, whh, 16, 516);
      if (l) {
        stage<512, 512>(a.dWihr + (size_t)((l - 1) * H + n0) * H, wir, 16, 516);
        stage<512, 512>(a.dst + ((size_t)(q * 4 + (l - 1)) * B + b0) * H, hin, 16, 516);
      } else if (s) {
        stage<512, 512>(a.dst + ((size_t)(p * 4 + 3) * B + b0) * H, hin, 16, 516);  // h3
      }
      stage<512, 512>(a.dst + ((size_t)(p * 4 + l) * B + b0) * H, hlc, 16, 516);
      __syncthreads();

      if (l == 0) {
        if (s == 0) {
          if (j == 0) {
            const float* xr = a.x + ((size_t)(b0 + bl) * T + (T - 1)) * 3;
            float v0 = xr[0], v1 = xr[1], v2 = xr[2];
            xinL[bl * 4 + 0] = v0; xinL[bl * 4 + 1] = v1; xinL[bl * 4 + 2] = v2;
            if (ntile == 0) {
              float* xw = a.xing + (size_t)(b0 + bl) * 4;  // parity 0
              xw[0] = v0; xw[1] = v1; xw[2] = v2;
            }
          }
        } else {
          const float* h3r = hin + bl * 516;
          float v = 0.f;
          for (int k = j; k < H; k += 16) v += h3r[k] * a.linW[k];
          v += __shfl_xor(v, 8); v += __shfl_xor(v, 4);
          v += __shfl_xor(v, 2); v += __shfl_xor(v, 1);
          float o0 = v + a.linb[0];
          const float* xp = a.xing + ((size_t)((s - 1) & 1) * B + (b0 + bl)) * 4;
          float sv1 = xp[0] - o0;
          float sv2 = xp[1] - sv1;
          if (j == 0) {
            xinL[bl * 4 + 0] = o0; xinL[bl * 4 + 1] = sv1; xinL[bl * 4 + 2] = sv2;
            if (ntile == 0) {
              float* xw = a.xing + ((size_t)(s & 1) * B + (b0 + bl)) * 4;
              xw[0] = o0; xw[1] = sv1; xw[2] = sv2;
              a.out[(size_t)(b0 + bl) * TGT + (s - 1)] = o0;
            }
          }
        }
        __syncthreads();
      }

      float acc = bias[l];
      if (l == 0) acc += xinL[bl * 4 + 0] * w00 + xinL[bl * 4 + 1] * w01 + xinL[bl * 4 + 2] * w02;
      const float* hr = hlc + bl * 516;
      const float* wr = whh + j * 516;
      float px = 0, py = 0, pz = 0, pw = 0;
      if (l) {
        const float* ir = hin + bl * 516;
        const float* vr = wir + j * 516;
#pragma unroll 4
        for (int k = 0; k < H; k += 4) {
          float4 hv = *(const float4*)(hr + k);
          float4 wv = *(const float4*)(wr + k);
          float4 iv = *(const float4*)(ir + k);
          float4 uv = *(const float4*)(vr + k);
          px += wv.x * hv.x + uv.x * iv.x; py += wv.y * hv.y + uv.y * iv.y;
          pz += wv.z * hv.z + uv.z * iv.z; pw += wv.w * hv.w + uv.w * iv.w;
        }
      } else {
#pragma unroll 4
        for (int k = 0; k < H; k += 4) {
          float4 hv = *(const float4*)(hr + k);
          float4 wv = *(const float4*)(wr + k);
          px += wv.x * hv.x; py += wv.y * hv.y; pz += wv.z * hv.z; pw += wv.w * hv.w;
        }
      }
      float hnew = tanhf(acc + (px + py) + (pz + pw));
      a.dst[((size_t)(q * 4 + l) * B + (b0 + bl)) * H + n] = hnew;
      bump(c);
    }

    if (ntile == 0) {  // final output column t=31 from dstate[0][3]
      waitc(c, 32u * 128);
      const float* h3g = a.dst + ((size_t)(0 * 4 + 3) * B + (b0 + bl)) * H;
      float v = 0.f;
      for (int k = j; k < H; k += 16) v += h3g[k] * a.linW[k];
      v += __shfl_xor(v, 8); v += __shfl_xor(v, 4);
      v += __shfl_xor(v, 2); v += __shfl_xor(v, 1);
      if (j == 0) a.out[(size_t)(b0 + bl) * TGT + 31] = v + a.linb[0];
    }
  }
}

// ---------------------------------------------------------------------------
extern "C" void kernel_launch(void* const* d_in, const int* in_sizes, int n_in,
                              void* d_out, int out_size, void* d_ws, size_t ws_size,
                              hipStream_t stream) {
  // ws layout (~66.0 MB): dstate 2MB | xing 4KB | ctr 256B | l0/G1 64MB
  float* dst  = (float*)d_ws;
  float* xing = dst + 2 * 4 * B * H;
  unsigned* ctr = (unsigned*)((char*)d_ws + 2101248);
  float* l0 = (float*)((char*)d_ws + 2101504);

  kinit<<<256, 256, 0, stream>>>(dst, ctr);

  Args args;
  args.x     = (const float*)d_in[0];
  args.eWih0 = (const float*)d_in[2];
  args.eWhh0 = (const float*)d_in[3];
  args.eWih1 = (const float*)d_in[4];
  args.eWhh1 = (const float*)d_in[5];
  args.ebih  = (const float*)d_in[6];
  args.ebhh  = (const float*)d_in[7];
  args.dWih0 = (const float*)d_in[8];
  args.dWihr = (const float*)d_in[9];
  args.dWhh  = (const float*)d_in[10];
  args.dbih  = (const float*)d_in[11];
  args.dbhh  = (const float*)d_in[12];
  args.linW  = (const float*)d_in[13];
  args.linb  = (const float*)d_in[14];
  args.dst = dst; args.xing = xing; args.l0 = l0; args.ctr = ctr;
  args.out = (float*)d_out;

  void* kp[] = { &args };
  hipLaunchCooperativeKernel((void*)birnn_all, dim3(256), dim3(256), kp, 0, stream);
}